// Round 21
// baseline (989.536 us; speedup 1.0000x reference)
//
#include <hip/hip_runtime.h>

typedef __attribute__((ext_vector_type(8))) short bf16x8;
typedef __attribute__((ext_vector_type(4))) float f32x4;
typedef unsigned short u16;

#define DEV static __device__ __forceinline__

constexpr int L = 131072;      // local tokens per batch
constexpr int NGT = 2048;      // global tokens per batch
constexpr int Cc = 192;
constexpr int OUTR = 133120;   // L + NG rows per batch in d_out
constexpr float SCALE = 0.1767766952966369f;  // 32^-0.5

DEV u16 f2bf(float f) {
  union { float f; unsigned u; } v; v.f = f;
  unsigned r = v.u + 0x7FFFu + ((v.u >> 16) & 1u);
  return (u16)(r >> 16);
}
DEV u16 f2bf_fast(float f) {   // single v_cvt_pk_bf16_f32 (RTNE), low half
  unsigned r;
  asm("v_cvt_pk_bf16_f32 %0, %1, %1" : "=v"(r) : "v"(f));
  return (u16)r;
}
DEV float bf2f(u16 v) {
  union { unsigned u; float f; } x; x.u = ((unsigned)v) << 16; return x.f;
}

// fast GELU, sigmoid form: gelu = v * sigmoid(2u); rcp via HW approx.
DEV float gelu_fast(float v) {
  float t = v * v;
  float w = v * fmaf(t, 0.0356774081f, 0.7978845608f);
  float e = __expf(-2.0f * w);
  return v * __builtin_amdgcn_rcpf(1.0f + e);
}

// row remap into d_out: 0=identity, 1=local stream, 2=global stream
template<int RM> DEV long rrow(int r) {
  if constexpr (RM == 1) return (long)(r >> 17) * OUTR + (r & (L - 1));
  else if constexpr (RM == 2) return (long)(r >> 11) * OUTR + L + (r & (NGT - 1));
  else return (long)r;
}
// runtime local/global d_out row mapping (wave-uniform isG)
DEV long rrow_rt(int r, bool isG) {
  return isG ? ((long)(r >> 11) * OUTR + L + (r & (NGT - 1)))
             : ((long)(r >> 17) * OUTR + (r & (L - 1)));
}

// window (n, t) -> flat token index l within one batch
DEV int win_l(int n, int t) {
  int sb = n >> 8, hb = (n >> 4) & 15, wb = n & 15;
  int si = t >> 4, hi = (t >> 2) & 3, wi = t & 3;
  return ((sb * 4 + si) << 12) + ((hb * 4 + hi) << 6) + (wb * 4 + wi);
}

DEV f32x4 mfma16(bf16x8 a, bf16x8 b, f32x4 c) {
  return __builtin_amdgcn_mfma_f32_16x16x32_bf16(a, b, c, 0, 0, 0);
}

#define GLL(srcp, dsto) __builtin_amdgcn_global_load_lds( \
    (const __attribute__((address_space(1))) void*)(srcp), \
    (__attribute__((address_space(3))) void*)(dsto), 16, 0, 0)

// ---------------- weight convert: out[n][k] = bf16(W[k][n]) ----------------------
__global__ __launch_bounds__(64)
void wconv_kernel(const float* __restrict__ W, u16* __restrict__ out, int K, int N) {
  int k = blockIdx.x * 64 + threadIdx.x;
  int n = blockIdx.y;
  out[(long)n * K + k] = f2bf(W[(long)k * N + n]);
}

// ---------------- local bias table: biasL[h][64][64] bf16 ------------------------
__global__ __launch_bounds__(256)
void lbias_kernel(const int* __restrict__ ridx, const float* __restrict__ rpb,
                  u16* __restrict__ biasL) {
  int gid = blockIdx.x * 256 + threadIdx.x;   // h*4096 + i*64 + j
  int j = gid & 63, i = (gid >> 6) & 63, h = gid >> 12;
  biasL[gid] = f2bf(rpb[ridx[i * 64 + j] * 6 + h]);
}

// ---------------- global bias precompute: biasG[h][2048][2048] (bf16) ------------
__global__ __launch_bounds__(256)
void gbias_kernel(const int* __restrict__ ridx, const float* __restrict__ rpb,
                  u16* __restrict__ biasG) {
  long gid = (long)blockIdx.x * 256 + threadIdx.x;
  int jg = (int)(gid & 255);
  long rest = gid >> 8;
  int i = (int)(rest & 2047);
  int h = (int)(rest >> 11);
  const int* ip = ridx + ((long)i << 11) + jg * 8;
  int idx[8];
  *(int4*)&idx[0] = *(const int4*)ip;
  *(int4*)&idx[4] = *(const int4*)(ip + 4);
  bf16x8 ov;
  #pragma unroll
  for (int j = 0; j < 8; j++) ov[j] = (short)f2bf(rpb[idx[j] * 6 + h]);
  *(bf16x8*)(biasG + (((long)h << 11) + i) * 2048 + jg * 8) = ov;
}

// ---------------- LayerNorm over C=192, bf16 out; 1 wave per row ----------------
template<int RM>
__global__ __launch_bounds__(256)
void ln_kernel(const float* __restrict__ in, const float* __restrict__ gam,
               const float* __restrict__ bet, u16* __restrict__ out) {
  int wid = threadIdx.x >> 6, lane = threadIdx.x & 63;
  int r = blockIdx.x * 4 + wid;
  const float* ip = in + rrow<RM>(r) * Cc;
  float x0 = ip[lane], x1 = ip[lane + 64], x2 = ip[lane + 128];
  float s = x0 + x1 + x2, s2 = x0 * x0 + x1 * x1 + x2 * x2;
  #pragma unroll
  for (int m = 32; m; m >>= 1) { s += __shfl_xor(s, m); s2 += __shfl_xor(s2, m); }
  float mean = s * (1.0f / 192.0f);
  float inv = rsqrtf(s2 * (1.0f / 192.0f) - mean * mean + 1e-5f);
  u16* op = out + (long)r * Cc;
  op[lane]       = f2bf_fast((x0 - mean) * inv * gam[lane]       + bet[lane]);
  op[lane + 64]  = f2bf_fast((x1 - mean) * inv * gam[lane + 64]  + bet[lane + 64]);
  op[lane + 128] = f2bf_fast((x2 - mean) * inv * gam[lane + 128] + bet[lane + 128]);
}

// ---------------- merged persistent-A GEMM (K=192), M=64 panel -------------------
// Grid = GBLK global blocks (first) + local blocks. Uniform runtime selection of
// A/out/res pointers; identical staging/compute to the proven gemmP.
template<bool GELU_, bool HASRES, bool OUTBF>
__global__ __launch_bounds__(256)
void gemmPm_kernel(const u16* __restrict__ AL, const u16* __restrict__ AG,
                   const u16* __restrict__ Bw, const float* __restrict__ bias,
                   const float* __restrict__ resL, const float* __restrict__ resG,
                   float* __restrict__ outF,
                   u16* __restrict__ outBL, u16* __restrict__ outBG, int N) {
  constexpr int KK = 192;
  constexpr int GBLK = 64;
  __shared__ u16 As[64 * KK];   // 24576 B, linear, row stride 384B
  __shared__ u16 Bs[64 * KK];   // 24576 B
  const int tid = threadIdx.x;
  const int lane = tid & 63, wid = tid >> 6;
  const int wm = wid >> 1, wn = wid & 1;
  const int r16 = lane & 15, kg = lane >> 4;
  const bool isG = blockIdx.x < GBLK;
  const u16* A = isG ? AG : AL;
  const float* res = isG ? resG : resL;
  u16* outB = isG ? outBG : outBL;
  const int m0 = (isG ? blockIdx.x : blockIdx.x - GBLK) * 64;
  #pragma unroll
  for (int c = 0; c < 6; c++) {
    int o = (c * 256 + tid) * 16;
    int row = o / 384, w = o - row * 384;
    int wsz = w ^ ((row & 7) << 4);
    GLL(A + (long)(m0 + row) * KK + (wsz >> 1), (char*)As + o);
  }
  int abase[2], asw[2], bbase[2], bsw[2];
  #pragma unroll
  for (int mi = 0; mi < 2; mi++) {
    int row = wm * 32 + mi * 16 + r16;
    abase[mi] = row * 384; asw[mi] = (row & 7) << 4;
  }
  #pragma unroll
  for (int ni = 0; ni < 2; ni++) {
    int row = wn * 32 + ni * 16 + r16;
    bbase[ni] = row * 384; bsw[ni] = (row & 7) << 4;
  }
  const int kgb = kg * 16;
  const int nbt = N >> 6;
  const int ntS = (blockIdx.x & 1) ? (nbt >> 1) : 0;   // phase stagger
  for (int it0 = 0; it0 < nbt; it0++) {
    const int nt = (ntS + it0) % nbt;
    if (it0) __syncthreads();
    #pragma unroll
    for (int c = 0; c < 6; c++) {
      int o = (c * 256 + tid) * 16;
      int row = o / 384, w = o - row * 384;
      int wsz = w ^ ((row & 7) << 4);
      GLL(Bw + (long)((nt << 6) + row) * KK + (wsz >> 1), (char*)Bs + o);
    }
    __syncthreads();
    f32x4 acc[2][2];
    #pragma unroll
    for (int i = 0; i < 2; i++) {
      acc[i][0] = f32x4{0.f, 0.f, 0.f, 0.f};
      acc[i][1] = f32x4{0.f, 0.f, 0.f, 0.f};
    }
    #pragma unroll
    for (int kk = 0; kk < 6; kk++) {
      const int kb = kk * 64 + kgb;
      bf16x8 af[2], bfv[2];
      #pragma unroll
      for (int mi = 0; mi < 2; mi++)
        af[mi] = *(const bf16x8*)((const char*)As + abase[mi] + (kb ^ asw[mi]));
      #pragma unroll
      for (int ni = 0; ni < 2; ni++)
        bfv[ni] = *(const bf16x8*)((const char*)Bs + bbase[ni] + (kb ^ bsw[ni]));
      #pragma unroll
      for (int mi = 0; mi < 2; mi++) {
        acc[mi][0] = mfma16(af[mi], bfv[0], acc[mi][0]);
        acc[mi][1] = mfma16(af[mi], bfv[1], acc[mi][1]);
      }
    }
    const int n0 = nt << 6;
    #pragma unroll
    for (int mi = 0; mi < 2; mi++)
      #pragma unroll
      for (int ni = 0; ni < 2; ni++)
        #pragma unroll
        for (int r = 0; r < 4; r++) {
          int row = m0 + wm * 32 + mi * 16 + kg * 4 + r;
          int col = n0 + wn * 32 + ni * 16 + r16;
          float v = acc[mi][ni][r] + bias[col];
          if constexpr (GELU_) v = gelu_fast(v);
          if constexpr (HASRES) v += res[(long)row * Cc + col];
          if constexpr (OUTBF) outB[(long)row * N + col] = f2bf_fast(v);
          else                 outF[rrow_rt(row, isG) * Cc + col] = v;
        }
  }
}

// ---------------- merged fused MLP: local + global streams in one grid -----------
// Grid = 64 global blocks (first) + 4096 local. 64-row panel, 512 threads /
// 8 waves; 12 hidden-chunks; LDS 80KB -> 2 blocks/CU; chunk-phase stagger;
// W1 prefetched during fc2 (W1s dead there).
__global__ __launch_bounds__(512)
void fusedmlp_kernel(const u16* __restrict__ xn2, const u16* __restrict__ gn2,
                     const u16* __restrict__ W1T, const float* __restrict__ fc1b,
                     const u16* __restrict__ W2T, const float* __restrict__ fc2b,
                     float* __restrict__ dout) {
  constexpr int GBLK = 64;
  __shared__ u16 Xs[64 * 192];   // 24576 B, stride 384
  __shared__ u16 W1s[64 * 192];  // 24576 B, stride 384
  __shared__ u16 W2s[192 * 64];  // 24576 B, stride 128
  __shared__ u16 Hs[64 * 64];    // 8192 B, stride 128
  const int tid = threadIdx.x;
  const int lane = tid & 63, wid = tid >> 6;      // wid 0..7
  const int wm = wid >> 1, wn = wid & 1;          // wm 0..3 (16 rows), wn 0..1
  const int r16 = lane & 15, kg = lane >> 4;
  const bool isG = blockIdx.x < GBLK;
  const u16* src = isG ? gn2 : xn2;
  const int m0 = (isG ? blockIdx.x : blockIdx.x - GBLK) * 64;
  const int hcS = (blockIdx.x & 1) * 6;           // phase stagger
  // per-thread staging coords
  int w1row[3], w1w[3], w2row[3], w2w[3];
  #pragma unroll
  for (int c = 0; c < 3; c++) {
    int o = (c * 512 + tid) * 16;
    w1row[c] = o / 384; w1w[c] = o - w1row[c] * 384;
    w2row[c] = o >> 7;  w2w[c] = o & 127;
  }
  // prologue: stage Xs + W1[hcS] + W2[hcS]
  #pragma unroll
  for (int c = 0; c < 3; c++) {
    int o = (c * 512 + tid) * 16;
    int row = o / 384, w = o - row * 384;
    int wsz = w ^ ((row & 7) << 4);
    GLL(src + (long)(m0 + row) * 192 + (wsz >> 1), (char*)Xs + o);
  }
  #pragma unroll
  for (int c = 0; c < 3; c++) {
    int o = (c * 512 + tid) * 16;
    int wsz = w1w[c] ^ ((w1row[c] & 7) << 4);
    GLL(W1T + (long)(hcS * 64 + w1row[c]) * 192 + (wsz >> 1), (char*)W1s + o);
  }
  #pragma unroll
  for (int c = 0; c < 3; c++) {
    int o = (c * 512 + tid) * 16;
    int wsz = w2w[c] ^ ((w2row[c] & 7) << 4);
    GLL(W2T + (long)w2row[c] * 768 + hcS * 64 + (wsz >> 1), (char*)W2s + o);
  }
  const int kgb = kg * 16;
  // fc1 fragment offsets
  int xbase, xsw, w1base[2], w1sw[2];
  {
    int row = wm * 16 + r16;
    xbase = row * 384; xsw = (row & 7) << 4;
  }
  #pragma unroll
  for (int ni = 0; ni < 2; ni++) {
    int row = wn * 32 + ni * 16 + r16;
    w1base[ni] = row * 384; w1sw[ni] = (row & 7) << 4;
  }
  // fc2 fragment offsets
  int hbase, hsw, w2base[6], w2sw[6];
  {
    int row = wm * 16 + r16;
    hbase = row * 128; hsw = (row & 7) << 4;
  }
  #pragma unroll
  for (int ni = 0; ni < 6; ni++) {
    int row = wn * 96 + ni * 16 + r16;
    w2base[ni] = row * 128; w2sw[ni] = (row & 7) << 4;
  }
  f32x4 acc2[6];
  #pragma unroll
  for (int ni = 0; ni < 6; ni++) acc2[ni] = f32x4{0.f, 0.f, 0.f, 0.f};

  for (int ic = 0; ic < 12; ic++) {
    const int hc = (hcS + ic) % 12;
    if (ic) {
      __syncthreads();     // A: prev fc2 done with W2s/Hs (also drains W1[hc] GLL)
      #pragma unroll
      for (int c = 0; c < 3; c++) {
        int o = (c * 512 + tid) * 16;
        int wsz = w2w[c] ^ ((w2row[c] & 7) << 4);
        GLL(W2T + (long)w2row[c] * 768 + hc * 64 + (wsz >> 1), (char*)W2s + o);
      }
    }
    __syncthreads();       // B: drain -> W1s/W2s (and Xs on ic=0) ready
    // fc1: 16x64 per wave
    f32x4 acc1[2];
    acc1[0] = f32x4{0.f, 0.f, 0.f, 0.f};
    acc1[1] = f32x4{0.f, 0.f, 0.f, 0.f};
    #pragma unroll
    for (int kk = 0; kk < 6; kk++) {
      const int kb = kk * 64 + kgb;
      bf16x8 af = *(const bf16x8*)((const char*)Xs + xbase + (kb ^ xsw));
      #pragma unroll
      for (int ni = 0; ni < 2; ni++) {
        bf16x8 bfv = *(const bf16x8*)((const char*)W1s + w1base[ni] + (kb ^ w1sw[ni]));
        acc1[ni] = mfma16(af, bfv, acc1[ni]);
      }
    }
    // gelu -> bf16 -> Hs (swizzled write matching fc2 A-read)
    #pragma unroll
    for (int ni = 0; ni < 2; ni++)
      #pragma unroll
      for (int r = 0; r < 4; r++) {
        int hrow = wm * 16 + kg * 4 + r;
        int hcol = wn * 32 + ni * 16 + r16;
        float v = acc1[ni][r] + fc1b[hc * 64 + hcol];
        v = gelu_fast(v);
        int byte = hrow * 128 + ((hcol * 2) ^ ((hrow & 7) << 4));
        *(u16*)((char*)Hs + byte) = f2bf_fast(v);
      }
    __syncthreads();       // C: Hs visible; ALL waves done with W1s
    // prefetch next chunk's W1 into the now-dead W1s (overlaps fc2 + barrier A)
    if (ic < 11) {
      const int nh = (hcS + ic + 1) % 12;
      #pragma unroll
      for (int c = 0; c < 3; c++) {
        int o = (c * 512 + tid) * 16;
        int wsz = w1w[c] ^ ((w1row[c] & 7) << 4);
        GLL(W1T + (long)(nh * 64 + w1row[c]) * 192 + (wsz >> 1), (char*)W1s + o);
      }
    }
    // fc2 partial: acc2 += h(16x64 per wave) @ W2c^T
    #pragma unroll
    for (int kk = 0; kk < 2; kk++) {
      const int kb = kk * 64 + kgb;
      bf16x8 af = *(const bf16x8*)((const char*)Hs + hbase + (kb ^ hsw));
      #pragma unroll
      for (int ni = 0; ni < 6; ni++) {
        bf16x8 bfv = *(const bf16x8*)((const char*)W2s + w2base[ni] + (kb ^ w2sw[ni]));
        acc2[ni] = mfma16(af, bfv, acc2[ni]);
      }
    }
  }
  // epilogue: bias + residual (in-place rows of dout)
  #pragma unroll
  for (int ni = 0; ni < 6; ni++)
    #pragma unroll
    for (int r = 0; r < 4; r++) {
      int row = m0 + wm * 16 + kg * 4 + r;
      int col = wn * 96 + ni * 16 + r16;
      long o = rrow_rt(row, isG) * Cc + col;
      dout[o] = acc2[ni][r] + fc2b[col] + dout[o];
    }
}

// ---------------- local window attention: one wave per (window, head) ------------
__global__ __launch_bounds__(256)
void wattn_kernel(const u16* __restrict__ qkv, const u16* __restrict__ biasL,
                  u16* __restrict__ aout) {
  __shared__ u16 smem[4 * 7424];
  const int tid = threadIdx.x, wid = tid >> 6, lane = tid & 63;
  const int task = blockIdx.x * 4 + wid;
  const int win = task / 6, h = task % 6;
  const int b = win >> 11, n = win & 2047;
  u16* Qs = smem + wid * 7424;
  u16* Ks = Qs + 2560;
  u16* Vt = Ks + 2560;
  u16* Ps = Qs;
  const int r16 = lane & 15, kg = lane >> 4;
  const long base = (long)b * L;
  #pragma unroll
  for (int ch = 0; ch < 4; ch++) {
    int cid = ch * 64 + lane;
    int tok = cid >> 2, seg = cid & 3;
    const u16* src = qkv + (base + win_l(n, tok)) * 576 + h * 32 + seg * 8;
    *(uint4*)&Qs[tok * 40 + seg * 8] = *(const uint4*)src;
    *(uint4*)&Ks[tok * 40 + seg * 8] = *(const uint4*)(src + 192);
    uint4 vv = *(const uint4*)(src + 384);
    const u16* ve = (const u16*)&vv;
    #pragma unroll
    for (int jj = 0; jj < 8; jj++) Vt[(seg * 8 + jj) * 72 + tok] = ve[jj];
  }
  __syncthreads();
  f32x4 s[4][4];
  #pragma unroll
  for (int it = 0; it < 4; it++) {
    bf16x8 aq = *(const bf16x8*)&Qs[(it * 16 + r16) * 40 + kg * 8];
    #pragma unroll
    for (int jt = 0; jt < 4; jt++) {
      bf16x8 bk = *(const bf16x8*)&Ks[(jt * 16 + r16) * 40 + kg * 8];
      s[it][jt] = mfma16(aq, bk, f32x4{0.f, 0.f, 0.f, 0.f});
    }
  }
  float inv_l[4][4];
  #pragma unroll
  for (int it = 0; it < 4; it++)
    #pragma unroll
    for (int r = 0; r < 4; r++) {
      int i = it * 16 + kg * 4 + r;
      const u16* bp = biasL + (h * 64 + i) * 64;
      #pragma unroll
      for (int jt = 0; jt < 4; jt++)
        s[it][jt][r] = s[it][jt][r] * SCALE + bf2f(bp[jt * 16 + r16]);
      float mx = fmaxf(fmaxf(s[it][0][r], s[it][1][r]), fmaxf(s[it][2][r], s[it][3][r]));
      #pragma unroll
      for (int msk = 1; msk < 16; msk <<= 1) mx = fmaxf(mx, __shfl_xor(mx, msk));
      float sum = 0.f;
      #pragma unroll
      for (int jt = 0; jt < 4; jt++) { float e = __expf(s[it][jt][r] - mx); s[it][jt][r] = e; sum += e; }
      #pragma unroll
      for (int msk = 1; msk < 16; msk <<= 1) sum += __shfl_xor(sum, msk);
      inv_l[it][r] = 1.0f / sum;
    }
  __syncthreads();
  #pragma unroll
  for (int it = 0; it < 4; it++)
    #pragma unroll
    for (int jt = 0; jt < 4; jt++)
      #pragma unroll
      for (int r = 0; r < 4; r++)
        Ps[(it * 16 + kg * 4 + r) * 72 + jt * 16 + r16] = f2bf_fast(s[it][jt][r]);
  __syncthreads();
  f32x4 o[4][2];
  #pragma unroll
  for (int it = 0; it < 4; it++) { o[it][0] = f32x4{0.f,0.f,0.f,0.f}; o[it][1] = f32x4{0.f,0.f,0.f,0.f}; }
  #pragma unroll
  for (int kk = 0; kk < 2; kk++) {
    bf16x8 vf0 = *(const bf16x8*)&Vt[r16 * 72 + kk * 32 + kg * 8];
    bf16x8 vf1 = *(const bf16x8*)&Vt[(16 + r16) * 72 + kk * 32 + kg * 8];
    #pragma unroll
    for (int it = 0; it < 4; it++) {
      bf16x8 pf = *(const bf16x8*)&Ps[(it * 16 + r16) * 72 + kk * 32 + kg * 8];
      o[it][0] = mfma16(pf, vf0, o[it][0]);
      o[it][1] = mfma16(pf, vf1, o[it][1]);
    }
  }
  #pragma unroll
  for (int it = 0; it < 4; it++)
    #pragma unroll
    for (int r = 0; r < 4; r++) {
      int tok = it * 16 + kg * 4 + r;
      long orow = (base + win_l(n, tok)) * 192 + h * 32;
      aout[orow + r16]      = f2bf_fast(o[it][0][r] * inv_l[it][r]);
      aout[orow + 16 + r16] = f2bf_fast(o[it][1][r] * inv_l[it][r]);
    }
}

// ---------------- global attention: flash, 4-way k-split per block ---------------
__global__ __launch_bounds__(256)
void gattn_kernel(const u16* __restrict__ qkvg, const u16* __restrict__ biasG,
                  u16* __restrict__ aout) {
  __shared__ u16 smem[4 * 4608];
  const int tid = threadIdx.x, wid = tid >> 6, lane = tid & 63;
  const int task = blockIdx.x;
  const int b = task / 384;
  const int rem = task % 384;
  const int h = rem >> 6, qt = rem & 63;
  u16* Vt = smem + wid * 4608;
  u16* Ps = Vt + 2304;
  const int r16 = lane & 15, kg = lane >> 4;
  const long gbase = (long)b * NGT;
  const int q0 = qt * 32;
  bf16x8 qf[2];
  #pragma unroll
  for (int it = 0; it < 2; it++)
    qf[it] = *(const bf16x8*)(qkvg + (gbase + q0 + it * 16 + r16) * 576 + h * 32 + kg * 8);
  f32x4 o[2][2];
  float m_[2][4], l_[2][4];
  #pragma unroll
  for (int it = 0; it < 2; it++) {
    o[it][0] = f32x4{0.f,0.f,0.f,0.f}; o[it][1] = f32x4{0.f,0.f,0.f,0.f};
    #pragma unroll
    for (int r = 0; r < 4; r++) { m_[it][r] = -1e30f; l_[it][r] = 0.f; }
  }
  for (int kt = wid; kt < 32; kt += 4) {
    #pragma unroll
    for (int ch = 0; ch < 4; ch++) {
      int cid = ch * 64 + lane;
      int tok = cid >> 2, seg = cid & 3;
      uint4 vv = *(const uint4*)(qkvg + (gbase + kt * 64 + tok) * 576 + 384 + h * 32 + seg * 8);
      const u16* ve = (const u16*)&vv;
      #pragma unroll
      for (int jj = 0; jj < 8; jj++) Vt[(seg * 8 + jj) * 72 + tok] = ve[jj];
    }
    f32x4 s[2][4];
    #pragma unroll
    for (int jt = 0; jt < 4; jt++) {
      bf16x8 kf = *(const bf16x8*)(qkvg + (gbase + kt * 64 + jt * 16 + r16) * 576 + 192 + h * 32 + kg * 8);
      #pragma unroll
      for (int it = 0; it < 2; it++) s[it][jt] = mfma16(qf[it], kf, f32x4{0.f,0.f,0.f,0.f});
    }
    #pragma unroll
    for (int it = 0; it < 2; it++)
      #pragma unroll
      for (int r = 0; r < 4; r++) {
        int i = q0 + it * 16 + kg * 4 + r;
        const u16* bp = biasG + (((long)h << 11) + i) * 2048 + kt * 64;
        float sv[4];
        #pragma unroll
        for (int jt = 0; jt < 4; jt++) sv[jt] = s[it][jt][r] * SCALE + bf2f(bp[jt * 16 + r16]);
        float tmx = fmaxf(fmaxf(sv[0], sv[1]), fmaxf(sv[2], sv[3]));
        #pragma unroll
        for (int msk = 1; msk < 16; msk <<= 1) tmx = fmaxf(tmx, __shfl_xor(tmx, msk));
        float mn = fmaxf(m_[it][r], tmx);
        float sc = __expf(m_[it][r] - mn);
        float sum = 0.f;
        #pragma unroll
        for (int jt = 0; jt < 4; jt++) {
          float e = __expf(sv[jt] - mn);
          sum += e;
          Ps[(it * 16 + kg * 4 + r) * 72 + jt * 16 + r16] = f2bf_fast(e);
        }
        #pragma unroll
        for (int msk = 1; msk < 16; msk <<= 1) sum += __shfl_xor(sum, msk);
        l_[it][r] = l_[it][r] * sc + sum;
        m_[it][r] = mn;
        o[it][0][r] *= sc; o[it][1][r] *= sc;
      }
    #pragma unroll
    for (int kk = 0; kk < 2; kk++) {
      bf16x8 vf0 = *(const bf16x8*)&Vt[r16 * 72 + kk * 32 + kg * 8];
      bf16x8 vf1 = *(const bf16x8*)&Vt[(16 + r16) * 72 + kk * 32 + kg * 8];
      #pragma unroll
      for (int it = 0; it < 2; it++) {
        bf16x8 pf = *(const bf16x8*)&Ps[(it * 16 + r16) * 72 + kk * 32 + kg * 8];
        o[it][0] = mfma16(pf, vf0, o[it][0]);
        o[it][1] = mfma16(pf, vf1, o[it][1]);
      }
    }
  }
  __syncthreads();
  float* Mm = (float*)smem;
  float* Lm = Mm + 128;
  float* Om = Lm + 128;
  #pragma unroll
  for (int it = 0; it < 2; it++)
    #pragma unroll
    for (int r = 0; r < 4; r++) {
      int row = it * 16 + kg * 4 + r;
      if (r16 == 0) { Mm[wid * 32 + row] = m_[it][r]; Lm[wid * 32 + row] = l_[it][r]; }
      Om[(wid * 32 + row) * 32 + r16]      = o[it][0][r];
      Om[(wid * 32 + row) * 32 + 16 + r16] = o[it][1][r];
    }
  __syncthreads();
  if (wid == 0) {
    #pragma unroll
    for (int it = 0; it < 2; it++)
      #pragma unroll
      for (int r = 0; r < 4; r++) {
        int row = it * 16 + kg * 4 + r;
        float mm = -1e30f;
        #pragma unroll
        for (int w = 0; w < 4; w++) mm = fmaxf(mm, Mm[w * 32 + row]);
        float ll = 0.f, o0 = 0.f, o1 = 0.f;
        #pragma unroll
        for (int w = 0; w < 4; w++) {
          float e = __expf(Mm[w * 32 + row] - mm);
          ll += e * Lm[w * 32 + row];
          o0 += e * Om[(w * 32 + row) * 32 + r16];
          o1 += e * Om[(w * 32 + row) * 32 + 16 + r16];
        }
        float inv = 1.0f / ll;
        long orow = (gbase + q0 + row) * 192 + h * 32;
        aout[orow + r16]      = f2bf_fast(o0 * inv);
        aout[orow + 16 + r16] = f2bf_fast(o1 * inv);
      }
  }
}

// ---------------- local<->global fuse (in place on d_out) ------------------------
__global__ __launch_bounds__(192)
void fuse_kernel(float* __restrict__ dout, const float* __restrict__ l2gw,
                 const float* __restrict__ l2gb) {
  const int bw = blockIdx.x;
  const int b = bw >> 11, n = bw & 2047;
  const int c = threadIdx.x;
  const long gro = ((long)b * OUTR + L + n) * 192 + c;
  const float g = dout[gro];
  float acc = 0.f;
  for (int t = 0; t < 64; t++) {
    long xro = ((long)b * OUTR + win_l(n, t)) * 192 + c;
    float v = dout[xro] + g;
    dout[xro] = v;
    acc += v * l2gw[t];
  }
  dout[gro] = g + acc + l2gb[0];
}

extern "C" void kernel_launch(void* const* d_in, const int* in_sizes, int n_in,
                              void* d_out, int out_size, void* d_ws, size_t ws_size,
                              hipStream_t stream) {
  (void)in_sizes; (void)n_in; (void)out_size; (void)ws_size;
  const float* x      = (const float*)d_in[0];
  const float* gx     = (const float*)d_in[1];
  const float* qkv_w  = (const float*)d_in[2];
  const float* qkv_b  = (const float*)d_in[3];
  const float* proj_w = (const float*)d_in[4];
  const float* proj_b = (const float*)d_in[5];
  const float* rpb_l  = (const float*)d_in[6];
  const float* rpb_g  = (const float*)d_in[7];
  const float* n1g    = (const float*)d_in[8];
  const float* n1b    = (const float*)d_in[9];
  const float* n2g    = (const float*)d_in[10];
  const float* n2b    = (const float*)d_in[11];
  const float* fc1w   = (const float*)d_in[12];
  const float* fc1b   = (const float*)d_in[13];
  const float* fc2w   = (const float*)d_in[14];
  const float* fc2b   = (const float*)d_in[15];
  const float* l2gw   = (const float*)d_in[16];
  const float* l2gb   = (const float*)d_in[17];
  const int*   ridx_l = (const int*)d_in[18];
  const int*   ridx_g = (const int*)d_in[19];
  float* out = (float*)d_out;
  char* ws = (char*)d_ws;

  // ws layout:
  u16* wqkvT = (u16*)(ws + 0);             // 576*192*2 = 221184
  u16* wprojT= (u16*)(ws + 221184);        // 192*192*2 = 73728
  u16* wfc1T = (u16*)(ws + 294912);        // 768*192*2 = 294912
  u16* wfc2T = (u16*)(ws + 589824);        // 192*768*2 = 294912
  u16* biasL = (u16*)(ws + 884736);        // 6*64*64*2 = 49152
  u16* xn    = (u16*)(ws + 1048576);       // slotA: xn -> attL -> xn2
  u16* qkvL  = (u16*)(ws + 101711872ll);   // slotB: qkvL(302MB)
  u16* biasG = (u16*)(ws + 403701760ll);   // 50331648
  u16* attG  = (u16*)(ws + 454033408ll);   // 1572864
  u16* gn    = (u16*)(ws + 504365056ll);   // slotC: gn -> gn2
  u16* qkvG  = (u16*)(ws + 505937920ll);   // slotD
  u16* attL = xn;
  u16* xn2  = xn;
  u16* gn2  = gn;

  // 0. precompute tables (inputs only)
  wconv_kernel<<<dim3(3, 576),  dim3(64), 0, stream>>>(qkv_w,  wqkvT, 192, 576);
  wconv_kernel<<<dim3(3, 192),  dim3(64), 0, stream>>>(proj_w, wprojT, 192, 192);
  wconv_kernel<<<dim3(3, 768),  dim3(64), 0, stream>>>(fc1w,   wfc1T, 192, 768);
  wconv_kernel<<<dim3(12, 192), dim3(64), 0, stream>>>(fc2w,   wfc2T, 768, 192);
  lbias_kernel<<<dim3(96),      dim3(256), 0, stream>>>(ridx_l, rpb_l, biasL);
  gbias_kernel<<<dim3(12288),   dim3(256), 0, stream>>>(ridx_g, rpb_g, biasG);
  // 1. LN1 (both streams)
  ln_kernel<0><<<dim3(65536), dim3(256), 0, stream>>>(x,  n1g, n1b, xn);
  ln_kernel<0><<<dim3(1024),  dim3(256), 0, stream>>>(gx, n1g, n1b, gn);
  // 2. QKV projections (merged: 64 global blocks first + 4096 local)
  gemmPm_kernel<false,false,true><<<dim3(4160), dim3(256), 0, stream>>>(
      xn, gn, wqkvT, qkv_b, nullptr, nullptr, nullptr, qkvL, qkvG, 576);
  // 3. attention
  wattn_kernel<<<dim3(6144), dim3(256), 0, stream>>>(qkvL, biasL, attL);
  gattn_kernel<<<dim3(768),  dim3(256), 0, stream>>>(qkvG, biasG, attG);
  // 4. proj + residual -> d_out (merged)
  gemmPm_kernel<false,true,false><<<dim3(4160), dim3(256), 0, stream>>>(
      attL, attG, wprojT, proj_b, x, gx, out, nullptr, nullptr, 192);
  // 5. local<->global fuse, in place on d_out (x2, g2)
  fuse_kernel<<<dim3(4096), dim3(192), 0, stream>>>(out, l2gw, l2gb);
  // 6. LN2 (both streams, read from d_out)
  ln_kernel<1><<<dim3(65536), dim3(256), 0, stream>>>((const float*)out, n2g, n2b, xn2);
  ln_kernel<2><<<dim3(1024),  dim3(256), 0, stream>>>((const float*)out, n2g, n2b, gn2);
  // 7+8. fused MLP (merged: 64 global blocks first + 4096 local)
  fusedmlp_kernel<<<dim3(4160), dim3(512), 0, stream>>>(
      xn2, gn2, wfc1T, fc1b, wfc2T, fc2b, out);
}

// Round 22
// 959.306 us; speedup vs baseline: 1.0315x; 1.0315x over previous
//
#include <hip/hip_runtime.h>

typedef __attribute__((ext_vector_type(8))) short bf16x8;
typedef __attribute__((ext_vector_type(4))) float f32x4;
typedef unsigned short u16;

#define DEV static __device__ __forceinline__

constexpr int L = 131072;      // local tokens per batch
constexpr int NGT = 2048;      // global tokens per batch
constexpr int Cc = 192;
constexpr int OUTR = 133120;   // L + NG rows per batch in d_out
constexpr float SCALE = 0.1767766952966369f;  // 32^-0.5

DEV u16 f2bf(float f) {
  union { float f; unsigned u; } v; v.f = f;
  unsigned r = v.u + 0x7FFFu + ((v.u >> 16) & 1u);
  return (u16)(r >> 16);
}
DEV u16 f2bf_fast(float f) {   // single v_cvt_pk_bf16_f32 (RTNE), low half
  unsigned r;
  asm("v_cvt_pk_bf16_f32 %0, %1, %1" : "=v"(r) : "v"(f));
  return (u16)r;
}
DEV float bf2f(u16 v) {
  union { unsigned u; float f; } x; x.u = ((unsigned)v) << 16; return x.f;
}

// fast GELU, sigmoid form: gelu = v * sigmoid(2u); rcp via HW approx.
DEV float gelu_fast(float v) {
  float t = v * v;
  float w = v * fmaf(t, 0.0356774081f, 0.7978845608f);
  float e = __expf(-2.0f * w);
  return v * __builtin_amdgcn_rcpf(1.0f + e);
}

// row remap into d_out: 0=identity, 1=local stream, 2=global stream
template<int RM> DEV long rrow(int r) {
  if constexpr (RM == 1) return (long)(r >> 17) * OUTR + (r & (L - 1));
  else if constexpr (RM == 2) return (long)(r >> 11) * OUTR + L + (r & (NGT - 1));
  else return (long)r;
}

// window (n, t) -> flat token index l within one batch
DEV int win_l(int n, int t) {
  int sb = n >> 8, hb = (n >> 4) & 15, wb = n & 15;
  int si = t >> 4, hi = (t >> 2) & 3, wi = t & 3;
  return ((sb * 4 + si) << 12) + ((hb * 4 + hi) << 6) + (wb * 4 + wi);
}

DEV f32x4 mfma16(bf16x8 a, bf16x8 b, f32x4 c) {
  return __builtin_amdgcn_mfma_f32_16x16x32_bf16(a, b, c, 0, 0, 0);
}

#define GLL(srcp, dsto) __builtin_amdgcn_global_load_lds( \
    (const __attribute__((address_space(1))) void*)(srcp), \
    (__attribute__((address_space(3))) void*)(dsto), 16, 0, 0)

// ---------------- weight convert: out[n][k] = bf16(W[k][n]) ----------------------
__global__ __launch_bounds__(64)
void wconv_kernel(const float* __restrict__ W, u16* __restrict__ out, int K, int N) {
  int k = blockIdx.x * 64 + threadIdx.x;
  int n = blockIdx.y;
  out[(long)n * K + k] = f2bf(W[(long)k * N + n]);
}

// ---------------- local bias table: biasL[h][64][64] bf16 ------------------------
__global__ __launch_bounds__(256)
void lbias_kernel(const int* __restrict__ ridx, const float* __restrict__ rpb,
                  u16* __restrict__ biasL) {
  int gid = blockIdx.x * 256 + threadIdx.x;   // h*4096 + i*64 + j
  int j = gid & 63, i = (gid >> 6) & 63, h = gid >> 12;
  biasL[gid] = f2bf(rpb[ridx[i * 64 + j] * 6 + h]);
}

// ---------------- global bias precompute: biasG[h][2048][2048] (bf16) ------------
__global__ __launch_bounds__(256)
void gbias_kernel(const int* __restrict__ ridx, const float* __restrict__ rpb,
                  u16* __restrict__ biasG) {
  long gid = (long)blockIdx.x * 256 + threadIdx.x;
  int jg = (int)(gid & 255);
  long rest = gid >> 8;
  int i = (int)(rest & 2047);
  int h = (int)(rest >> 11);
  const int* ip = ridx + ((long)i << 11) + jg * 8;
  int idx[8];
  *(int4*)&idx[0] = *(const int4*)ip;
  *(int4*)&idx[4] = *(const int4*)(ip + 4);
  bf16x8 ov;
  #pragma unroll
  for (int j = 0; j < 8; j++) ov[j] = (short)f2bf(rpb[idx[j] * 6 + h]);
  *(bf16x8*)(biasG + (((long)h << 11) + i) * 2048 + jg * 8) = ov;
}

// ---------------- LayerNorm over C=192, bf16 out; 1 wave per row ----------------
template<int RM>
__global__ __launch_bounds__(256)
void ln_kernel(const float* __restrict__ in, const float* __restrict__ gam,
               const float* __restrict__ bet, u16* __restrict__ out) {
  int wid = threadIdx.x >> 6, lane = threadIdx.x & 63;
  int r = blockIdx.x * 4 + wid;
  const float* ip = in + rrow<RM>(r) * Cc;
  float x0 = ip[lane], x1 = ip[lane + 64], x2 = ip[lane + 128];
  float s = x0 + x1 + x2, s2 = x0 * x0 + x1 * x1 + x2 * x2;
  #pragma unroll
  for (int m = 32; m; m >>= 1) { s += __shfl_xor(s, m); s2 += __shfl_xor(s2, m); }
  float mean = s * (1.0f / 192.0f);
  float inv = rsqrtf(s2 * (1.0f / 192.0f) - mean * mean + 1e-5f);
  u16* op = out + (long)r * Cc;
  op[lane]       = f2bf_fast((x0 - mean) * inv * gam[lane]       + bet[lane]);
  op[lane + 64]  = f2bf_fast((x1 - mean) * inv * gam[lane + 64]  + bet[lane + 64]);
  op[lane + 128] = f2bf_fast((x2 - mean) * inv * gam[lane + 128] + bet[lane + 128]);
}

// ---------------- persistent-A GEMM (K=192), M=64 panel, gll-staged --------------
// n-tile loop order staggered by block parity (outputs independent per nt) so
// co-resident blocks' staging drains overlap the other's MFMA.
template<bool GELU_, bool HASRES, int RMO, int RMR, bool OUTBF>
__global__ __launch_bounds__(256)
void gemmP_kernel(const u16* __restrict__ A, const u16* __restrict__ Bw,
                  const float* __restrict__ bias, const float* __restrict__ res,
                  float* __restrict__ outF, u16* __restrict__ outB, int N) {
  constexpr int KK = 192;
  __shared__ u16 As[64 * KK];   // 24576 B, linear, row stride 384B
  __shared__ u16 Bs[64 * KK];   // 24576 B
  const int tid = threadIdx.x;
  const int lane = tid & 63, wid = tid >> 6;
  const int wm = wid >> 1, wn = wid & 1;
  const int r16 = lane & 15, kg = lane >> 4;
  const int m0 = blockIdx.x * 64;
  #pragma unroll
  for (int c = 0; c < 6; c++) {
    int o = (c * 256 + tid) * 16;
    int row = o / 384, w = o - row * 384;
    int wsz = w ^ ((row & 7) << 4);
    GLL(A + (long)(m0 + row) * KK + (wsz >> 1), (char*)As + o);
  }
  int abase[2], asw[2], bbase[2], bsw[2];
  #pragma unroll
  for (int mi = 0; mi < 2; mi++) {
    int row = wm * 32 + mi * 16 + r16;
    abase[mi] = row * 384; asw[mi] = (row & 7) << 4;
  }
  #pragma unroll
  for (int ni = 0; ni < 2; ni++) {
    int row = wn * 32 + ni * 16 + r16;
    bbase[ni] = row * 384; bsw[ni] = (row & 7) << 4;
  }
  const int kgb = kg * 16;
  const int nbt = N >> 6;
  const int ntS = (blockIdx.x & 1) ? (nbt >> 1) : 0;   // phase stagger
  for (int it0 = 0; it0 < nbt; it0++) {
    const int nt = (ntS + it0) % nbt;
    if (it0) __syncthreads();
    #pragma unroll
    for (int c = 0; c < 6; c++) {
      int o = (c * 256 + tid) * 16;
      int row = o / 384, w = o - row * 384;
      int wsz = w ^ ((row & 7) << 4);
      GLL(Bw + (long)((nt << 6) + row) * KK + (wsz >> 1), (char*)Bs + o);
    }
    __syncthreads();
    f32x4 acc[2][2];
    #pragma unroll
    for (int i = 0; i < 2; i++) {
      acc[i][0] = f32x4{0.f, 0.f, 0.f, 0.f};
      acc[i][1] = f32x4{0.f, 0.f, 0.f, 0.f};
    }
    #pragma unroll
    for (int kk = 0; kk < 6; kk++) {
      const int kb = kk * 64 + kgb;
      bf16x8 af[2], bfv[2];
      #pragma unroll
      for (int mi = 0; mi < 2; mi++)
        af[mi] = *(const bf16x8*)((const char*)As + abase[mi] + (kb ^ asw[mi]));
      #pragma unroll
      for (int ni = 0; ni < 2; ni++)
        bfv[ni] = *(const bf16x8*)((const char*)Bs + bbase[ni] + (kb ^ bsw[ni]));
      #pragma unroll
      for (int mi = 0; mi < 2; mi++) {
        acc[mi][0] = mfma16(af[mi], bfv[0], acc[mi][0]);
        acc[mi][1] = mfma16(af[mi], bfv[1], acc[mi][1]);
      }
    }
    const int n0 = nt << 6;
    #pragma unroll
    for (int mi = 0; mi < 2; mi++)
      #pragma unroll
      for (int ni = 0; ni < 2; ni++)
        #pragma unroll
        for (int r = 0; r < 4; r++) {
          int row = m0 + wm * 32 + mi * 16 + kg * 4 + r;
          int col = n0 + wn * 32 + ni * 16 + r16;
          float v = acc[mi][ni][r] + bias[col];
          if constexpr (GELU_) v = gelu_fast(v);
          if constexpr (HASRES) v += res[rrow<RMR>(row) * Cc + col];
          if constexpr (OUTBF) outB[(long)row * N + col] = f2bf_fast(v);
          else                 outF[rrow<RMO>(row) * Cc + col] = v;
        }
  }
}

// ---------------- fused MLP v8: round-16 schedule + chunk-phase stagger ----------
// 64-row panel, 512 threads / 8 waves; 12 hidden-chunks; LDS 80KB -> 2 blocks/CU.
// acc2 is a sum over chunks (order-free): odd blocks start at hc=6 so the two
// co-resident blocks' staging drains overlap the other's fc1/fc2 compute.
// W1 prefetched during fc2 (W1s dead there).
template<int RM>
__global__ __launch_bounds__(512)
void fusedmlp_kernel(const u16* __restrict__ xn2, const u16* __restrict__ W1T,
                     const float* __restrict__ fc1b, const u16* __restrict__ W2T,
                     const float* __restrict__ fc2b, float* __restrict__ dout) {
  __shared__ u16 Xs[64 * 192];   // 24576 B, stride 384
  __shared__ u16 W1s[64 * 192];  // 24576 B, stride 384
  __shared__ u16 W2s[192 * 64];  // 24576 B, stride 128
  __shared__ u16 Hs[64 * 64];    // 8192 B, stride 128
  const int tid = threadIdx.x;
  const int lane = tid & 63, wid = tid >> 6;      // wid 0..7
  const int wm = wid >> 1, wn = wid & 1;          // wm 0..3 (16 rows), wn 0..1
  const int r16 = lane & 15, kg = lane >> 4;
  const int m0 = blockIdx.x * 64;
  const int hcS = (blockIdx.x & 1) * 6;           // phase stagger
  // per-thread staging coords
  int w1row[3], w1w[3], w2row[3], w2w[3];
  #pragma unroll
  for (int c = 0; c < 3; c++) {
    int o = (c * 512 + tid) * 16;
    w1row[c] = o / 384; w1w[c] = o - w1row[c] * 384;
    w2row[c] = o >> 7;  w2w[c] = o & 127;
  }
  // prologue: stage Xs + W1[hcS] + W2[hcS]
  #pragma unroll
  for (int c = 0; c < 3; c++) {
    int o = (c * 512 + tid) * 16;
    int row = o / 384, w = o - row * 384;
    int wsz = w ^ ((row & 7) << 4);
    GLL(xn2 + (long)(m0 + row) * 192 + (wsz >> 1), (char*)Xs + o);
  }
  #pragma unroll
  for (int c = 0; c < 3; c++) {
    int o = (c * 512 + tid) * 16;
    int wsz = w1w[c] ^ ((w1row[c] & 7) << 4);
    GLL(W1T + (long)(hcS * 64 + w1row[c]) * 192 + (wsz >> 1), (char*)W1s + o);
  }
  #pragma unroll
  for (int c = 0; c < 3; c++) {
    int o = (c * 512 + tid) * 16;
    int wsz = w2w[c] ^ ((w2row[c] & 7) << 4);
    GLL(W2T + (long)w2row[c] * 768 + hcS * 64 + (wsz >> 1), (char*)W2s + o);
  }
  const int kgb = kg * 16;
  // fc1 fragment offsets
  int xbase, xsw, w1base[2], w1sw[2];
  {
    int row = wm * 16 + r16;
    xbase = row * 384; xsw = (row & 7) << 4;
  }
  #pragma unroll
  for (int ni = 0; ni < 2; ni++) {
    int row = wn * 32 + ni * 16 + r16;
    w1base[ni] = row * 384; w1sw[ni] = (row & 7) << 4;
  }
  // fc2 fragment offsets
  int hbase, hsw, w2base[6], w2sw[6];
  {
    int row = wm * 16 + r16;
    hbase = row * 128; hsw = (row & 7) << 4;
  }
  #pragma unroll
  for (int ni = 0; ni < 6; ni++) {
    int row = wn * 96 + ni * 16 + r16;
    w2base[ni] = row * 128; w2sw[ni] = (row & 7) << 4;
  }
  f32x4 acc2[6];
  #pragma unroll
  for (int ni = 0; ni < 6; ni++) acc2[ni] = f32x4{0.f, 0.f, 0.f, 0.f};

  for (int ic = 0; ic < 12; ic++) {
    const int hc = (hcS + ic) % 12;
    if (ic) {
      __syncthreads();     // A: prev fc2 done with W2s/Hs (also drains W1[hc] GLL)
      #pragma unroll
      for (int c = 0; c < 3; c++) {
        int o = (c * 512 + tid) * 16;
        int wsz = w2w[c] ^ ((w2row[c] & 7) << 4);
        GLL(W2T + (long)w2row[c] * 768 + hc * 64 + (wsz >> 1), (char*)W2s + o);
      }
    }
    __syncthreads();       // B: drain -> W1s/W2s (and Xs on ic=0) ready
    // fc1: 16x64 per wave
    f32x4 acc1[2];
    acc1[0] = f32x4{0.f, 0.f, 0.f, 0.f};
    acc1[1] = f32x4{0.f, 0.f, 0.f, 0.f};
    #pragma unroll
    for (int kk = 0; kk < 6; kk++) {
      const int kb = kk * 64 + kgb;
      bf16x8 af = *(const bf16x8*)((const char*)Xs + xbase + (kb ^ xsw));
      #pragma unroll
      for (int ni = 0; ni < 2; ni++) {
        bf16x8 bfv = *(const bf16x8*)((const char*)W1s + w1base[ni] + (kb ^ w1sw[ni]));
        acc1[ni] = mfma16(af, bfv, acc1[ni]);
      }
    }
    // gelu -> bf16 -> Hs (swizzled write matching fc2 A-read)
    #pragma unroll
    for (int ni = 0; ni < 2; ni++)
      #pragma unroll
      for (int r = 0; r < 4; r++) {
        int hrow = wm * 16 + kg * 4 + r;
        int hcol = wn * 32 + ni * 16 + r16;
        float v = acc1[ni][r] + fc1b[hc * 64 + hcol];
        v = gelu_fast(v);
        int byte = hrow * 128 + ((hcol * 2) ^ ((hrow & 7) << 4));
        *(u16*)((char*)Hs + byte) = f2bf_fast(v);
      }
    __syncthreads();       // C: Hs visible; ALL waves done with W1s
    // prefetch next chunk's W1 into the now-dead W1s (overlaps fc2 + barrier A)
    if (ic < 11) {
      const int nh = (hcS + ic + 1) % 12;
      #pragma unroll
      for (int c = 0; c < 3; c++) {
        int o = (c * 512 + tid) * 16;
        int wsz = w1w[c] ^ ((w1row[c] & 7) << 4);
        GLL(W1T + (long)(nh * 64 + w1row[c]) * 192 + (wsz >> 1), (char*)W1s + o);
      }
    }
    // fc2 partial: acc2 += h(16x64 per wave) @ W2c^T
    #pragma unroll
    for (int kk = 0; kk < 2; kk++) {
      const int kb = kk * 64 + kgb;
      bf16x8 af = *(const bf16x8*)((const char*)Hs + hbase + (kb ^ hsw));
      #pragma unroll
      for (int ni = 0; ni < 6; ni++) {
        bf16x8 bfv = *(const bf16x8*)((const char*)W2s + w2base[ni] + (kb ^ w2sw[ni]));
        acc2[ni] = mfma16(af, bfv, acc2[ni]);
      }
    }
  }
  // epilogue: bias + residual (in-place rows of dout)
  #pragma unroll
  for (int ni = 0; ni < 6; ni++)
    #pragma unroll
    for (int r = 0; r < 4; r++) {
      int row = m0 + wm * 16 + kg * 4 + r;
      int col = wn * 96 + ni * 16 + r16;
      long o = rrow<RM>(row) * Cc + col;
      dout[o] = acc2[ni][r] + fc2b[col] + dout[o];
    }
}

// ---------------- GEMM (general K): m97-style ------------------------------------
template<bool GELU_, bool HASRES, int RMO, int RMR, bool OUTBF>
__global__ __launch_bounds__(256)
void gemm_kernel(const u16* __restrict__ A, const u16* __restrict__ Bw,
                 const float* __restrict__ bias, const float* __restrict__ res,
                 float* __restrict__ outF, u16* __restrict__ outB,
                 int M, int N, int K) {
  __shared__ u16 AsL[128 * 64];
  __shared__ u16 BsL[64 * 64];
  const int tid = threadIdx.x;
  const int lane = tid & 63, wid = tid >> 6;
  const int wm = wid >> 1, wn = wid & 1;
  const int r16 = lane & 15, kg = lane >> 4;
  const int m0 = blockIdx.y * 128, n0 = blockIdx.x * 64;
  f32x4 acc[4][2];
  #pragma unroll
  for (int i = 0; i < 4; i++) {
    acc[i][0] = f32x4{0.f, 0.f, 0.f, 0.f};
    acc[i][1] = f32x4{0.f, 0.f, 0.f, 0.f};
  }
  int aoff[4], boff[2];
  #pragma unroll
  for (int mi = 0; mi < 4; mi++) {
    int row = wm * 64 + mi * 16 + r16;
    aoff[mi] = (row << 7) ^ ((row & 7) << 4);
  }
  #pragma unroll
  for (int ni = 0; ni < 2; ni++) {
    int row = wn * 32 + ni * 16 + r16;
    boff[ni] = (row << 7) ^ ((row & 7) << 4);
  }
  const int kgb = kg * 16;

  for (int k0 = 0; k0 < K; k0 += 64) {
    __syncthreads();
    #pragma unroll
    for (int c = 0; c < 4; c++) {
      int o = (c * 256 + tid) * 16;
      int row = o >> 7, w = o & 127;
      int wsz = w ^ ((row & 7) << 4);
      GLL(A + (long)(m0 + row) * K + k0 + (wsz >> 1), (char*)AsL + o);
    }
    #pragma unroll
    for (int c = 0; c < 2; c++) {
      int o = (c * 256 + tid) * 16;
      int row = o >> 7, w = o & 127;
      int wsz = w ^ ((row & 7) << 4);
      GLL(Bw + (long)(n0 + row) * K + k0 + (wsz >> 1), (char*)BsL + o);
    }
    __syncthreads();
    #pragma unroll
    for (int kk = 0; kk < 2; kk++) {
      bf16x8 af[4], bfv[2];
      #pragma unroll
      for (int mi = 0; mi < 4; mi++)
        af[mi] = *(const bf16x8*)((const char*)AsL + (aoff[mi] ^ (kk * 64 + kgb)));
      #pragma unroll
      for (int ni = 0; ni < 2; ni++)
        bfv[ni] = *(const bf16x8*)((const char*)BsL + (boff[ni] ^ (kk * 64 + kgb)));
      #pragma unroll
      for (int mi = 0; mi < 4; mi++) {
        acc[mi][0] = mfma16(af[mi], bfv[0], acc[mi][0]);
        acc[mi][1] = mfma16(af[mi], bfv[1], acc[mi][1]);
      }
    }
  }
  #pragma unroll
  for (int mi = 0; mi < 4; mi++)
    #pragma unroll
    for (int ni = 0; ni < 2; ni++)
      #pragma unroll
      for (int r = 0; r < 4; r++) {
        int row = m0 + wm * 64 + mi * 16 + kg * 4 + r;
        int col = n0 + wn * 32 + ni * 16 + r16;
        float v = acc[mi][ni][r] + bias[col];
        if constexpr (GELU_) v = gelu_fast(v);
        if constexpr (HASRES) v += res[rrow<RMR>(row) * Cc + col];
        if constexpr (OUTBF) outB[(long)row * N + col] = f2bf_fast(v);
        else                 outF[rrow<RMO>(row) * Cc + col] = v;
      }
}

// ---------------- local window attention: one wave per (window, head) ------------
__global__ __launch_bounds__(256)
void wattn_kernel(const u16* __restrict__ qkv, const u16* __restrict__ biasL,
                  u16* __restrict__ aout) {
  __shared__ u16 smem[4 * 7424];
  const int tid = threadIdx.x, wid = tid >> 6, lane = tid & 63;
  const int task = blockIdx.x * 4 + wid;
  const int win = task / 6, h = task % 6;
  const int b = win >> 11, n = win & 2047;
  u16* Qs = smem + wid * 7424;
  u16* Ks = Qs + 2560;
  u16* Vt = Ks + 2560;
  u16* Ps = Qs;
  const int r16 = lane & 15, kg = lane >> 4;
  const long base = (long)b * L;
  #pragma unroll
  for (int ch = 0; ch < 4; ch++) {
    int cid = ch * 64 + lane;
    int tok = cid >> 2, seg = cid & 3;
    const u16* src = qkv + (base + win_l(n, tok)) * 576 + h * 32 + seg * 8;
    *(uint4*)&Qs[tok * 40 + seg * 8] = *(const uint4*)src;
    *(uint4*)&Ks[tok * 40 + seg * 8] = *(const uint4*)(src + 192);
    uint4 vv = *(const uint4*)(src + 384);
    const u16* ve = (const u16*)&vv;
    #pragma unroll
    for (int jj = 0; jj < 8; jj++) Vt[(seg * 8 + jj) * 72 + tok] = ve[jj];
  }
  __syncthreads();
  f32x4 s[4][4];
  #pragma unroll
  for (int it = 0; it < 4; it++) {
    bf16x8 aq = *(const bf16x8*)&Qs[(it * 16 + r16) * 40 + kg * 8];
    #pragma unroll
    for (int jt = 0; jt < 4; jt++) {
      bf16x8 bk = *(const bf16x8*)&Ks[(jt * 16 + r16) * 40 + kg * 8];
      s[it][jt] = mfma16(aq, bk, f32x4{0.f, 0.f, 0.f, 0.f});
    }
  }
  float inv_l[4][4];
  #pragma unroll
  for (int it = 0; it < 4; it++)
    #pragma unroll
    for (int r = 0; r < 4; r++) {
      int i = it * 16 + kg * 4 + r;
      const u16* bp = biasL + (h * 64 + i) * 64;
      #pragma unroll
      for (int jt = 0; jt < 4; jt++)
        s[it][jt][r] = s[it][jt][r] * SCALE + bf2f(bp[jt * 16 + r16]);
      float mx = fmaxf(fmaxf(s[it][0][r], s[it][1][r]), fmaxf(s[it][2][r], s[it][3][r]));
      #pragma unroll
      for (int msk = 1; msk < 16; msk <<= 1) mx = fmaxf(mx, __shfl_xor(mx, msk));
      float sum = 0.f;
      #pragma unroll
      for (int jt = 0; jt < 4; jt++) { float e = __expf(s[it][jt][r] - mx); s[it][jt][r] = e; sum += e; }
      #pragma unroll
      for (int msk = 1; msk < 16; msk <<= 1) sum += __shfl_xor(sum, msk);
      inv_l[it][r] = 1.0f / sum;
    }
  __syncthreads();
  #pragma unroll
  for (int it = 0; it < 4; it++)
    #pragma unroll
    for (int jt = 0; jt < 4; jt++)
      #pragma unroll
      for (int r = 0; r < 4; r++)
        Ps[(it * 16 + kg * 4 + r) * 72 + jt * 16 + r16] = f2bf_fast(s[it][jt][r]);
  __syncthreads();
  f32x4 o[4][2];
  #pragma unroll
  for (int it = 0; it < 4; it++) { o[it][0] = f32x4{0.f,0.f,0.f,0.f}; o[it][1] = f32x4{0.f,0.f,0.f,0.f}; }
  #pragma unroll
  for (int kk = 0; kk < 2; kk++) {
    bf16x8 vf0 = *(const bf16x8*)&Vt[r16 * 72 + kk * 32 + kg * 8];
    bf16x8 vf1 = *(const bf16x8*)&Vt[(16 + r16) * 72 + kk * 32 + kg * 8];
    #pragma unroll
    for (int it = 0; it < 4; it++) {
      bf16x8 pf = *(const bf16x8*)&Ps[(it * 16 + r16) * 72 + kk * 32 + kg * 8];
      o[it][0] = mfma16(pf, vf0, o[it][0]);
      o[it][1] = mfma16(pf, vf1, o[it][1]);
    }
  }
  #pragma unroll
  for (int it = 0; it < 4; it++)
    #pragma unroll
    for (int r = 0; r < 4; r++) {
      int tok = it * 16 + kg * 4 + r;
      long orow = (base + win_l(n, tok)) * 192 + h * 32;
      aout[orow + r16]      = f2bf_fast(o[it][0][r] * inv_l[it][r]);
      aout[orow + 16 + r16] = f2bf_fast(o[it][1][r] * inv_l[it][r]);
    }
}

// ---------------- global attention: flash, 4-way k-split per block ---------------
__global__ __launch_bounds__(256)
void gattn_kernel(const u16* __restrict__ qkvg, const u16* __restrict__ biasG,
                  u16* __restrict__ aout) {
  __shared__ u16 smem[4 * 4608];
  const int tid = threadIdx.x, wid = tid >> 6, lane = tid & 63;
  const int task = blockIdx.x;
  const int b = task / 384;
  const int rem = task % 384;
  const int h = rem >> 6, qt = rem & 63;
  u16* Vt = smem + wid * 4608;
  u16* Ps = Vt + 2304;
  const int r16 = lane & 15, kg = lane >> 4;
  const long gbase = (long)b * NGT;
  const int q0 = qt * 32;
  bf16x8 qf[2];
  #pragma unroll
  for (int it = 0; it < 2; it++)
    qf[it] = *(const bf16x8*)(qkvg + (gbase + q0 + it * 16 + r16) * 576 + h * 32 + kg * 8);
  f32x4 o[2][2];
  float m_[2][4], l_[2][4];
  #pragma unroll
  for (int it = 0; it < 2; it++) {
    o[it][0] = f32x4{0.f,0.f,0.f,0.f}; o[it][1] = f32x4{0.f,0.f,0.f,0.f};
    #pragma unroll
    for (int r = 0; r < 4; r++) { m_[it][r] = -1e30f; l_[it][r] = 0.f; }
  }
  for (int kt = wid; kt < 32; kt += 4) {
    #pragma unroll
    for (int ch = 0; ch < 4; ch++) {
      int cid = ch * 64 + lane;
      int tok = cid >> 2, seg = cid & 3;
      uint4 vv = *(const uint4*)(qkvg + (gbase + kt * 64 + tok) * 576 + 384 + h * 32 + seg * 8);
      const u16* ve = (const u16*)&vv;
      #pragma unroll
      for (int jj = 0; jj < 8; jj++) Vt[(seg * 8 + jj) * 72 + tok] = ve[jj];
    }
    f32x4 s[2][4];
    #pragma unroll
    for (int jt = 0; jt < 4; jt++) {
      bf16x8 kf = *(const bf16x8*)(qkvg + (gbase + kt * 64 + jt * 16 + r16) * 576 + 192 + h * 32 + kg * 8);
      #pragma unroll
      for (int it = 0; it < 2; it++) s[it][jt] = mfma16(qf[it], kf, f32x4{0.f,0.f,0.f,0.f});
    }
    #pragma unroll
    for (int it = 0; it < 2; it++)
      #pragma unroll
      for (int r = 0; r < 4; r++) {
        int i = q0 + it * 16 + kg * 4 + r;
        const u16* bp = biasG + (((long)h << 11) + i) * 2048 + kt * 64;
        float sv[4];
        #pragma unroll
        for (int jt = 0; jt < 4; jt++) sv[jt] = s[it][jt][r] * SCALE + bf2f(bp[jt * 16 + r16]);
        float tmx = fmaxf(fmaxf(sv[0], sv[1]), fmaxf(sv[2], sv[3]));
        #pragma unroll
        for (int msk = 1; msk < 16; msk <<= 1) tmx = fmaxf(tmx, __shfl_xor(tmx, msk));
        float mn = fmaxf(m_[it][r], tmx);
        float sc = __expf(m_[it][r] - mn);
        float sum = 0.f;
        #pragma unroll
        for (int jt = 0; jt < 4; jt++) {
          float e = __expf(sv[jt] - mn);
          sum += e;
          Ps[(it * 16 + kg * 4 + r) * 72 + jt * 16 + r16] = f2bf_fast(e);
        }
        #pragma unroll
        for (int msk = 1; msk < 16; msk <<= 1) sum += __shfl_xor(sum, msk);
        l_[it][r] = l_[it][r] * sc + sum;
        m_[it][r] = mn;
        o[it][0][r] *= sc; o[it][1][r] *= sc;
      }
    #pragma unroll
    for (int kk = 0; kk < 2; kk++) {
      bf16x8 vf0 = *(const bf16x8*)&Vt[r16 * 72 + kk * 32 + kg * 8];
      bf16x8 vf1 = *(const bf16x8*)&Vt[(16 + r16) * 72 + kk * 32 + kg * 8];
      #pragma unroll
      for (int it = 0; it < 2; it++) {
        bf16x8 pf = *(const bf16x8*)&Ps[(it * 16 + r16) * 72 + kk * 32 + kg * 8];
        o[it][0] = mfma16(pf, vf0, o[it][0]);
        o[it][1] = mfma16(pf, vf1, o[it][1]);
      }
    }
  }
  __syncthreads();
  float* Mm = (float*)smem;
  float* Lm = Mm + 128;
  float* Om = Lm + 128;
  #pragma unroll
  for (int it = 0; it < 2; it++)
    #pragma unroll
    for (int r = 0; r < 4; r++) {
      int row = it * 16 + kg * 4 + r;
      if (r16 == 0) { Mm[wid * 32 + row] = m_[it][r]; Lm[wid * 32 + row] = l_[it][r]; }
      Om[(wid * 32 + row) * 32 + r16]      = o[it][0][r];
      Om[(wid * 32 + row) * 32 + 16 + r16] = o[it][1][r];
    }
  __syncthreads();
  if (wid == 0) {
    #pragma unroll
    for (int it = 0; it < 2; it++)
      #pragma unroll
      for (int r = 0; r < 4; r++) {
        int row = it * 16 + kg * 4 + r;
        float mm = -1e30f;
        #pragma unroll
        for (int w = 0; w < 4; w++) mm = fmaxf(mm, Mm[w * 32 + row]);
        float ll = 0.f, o0 = 0.f, o1 = 0.f;
        #pragma unroll
        for (int w = 0; w < 4; w++) {
          float e = __expf(Mm[w * 32 + row] - mm);
          ll += e * Lm[w * 32 + row];
          o0 += e * Om[(w * 32 + row) * 32 + r16];
          o1 += e * Om[(w * 32 + row) * 32 + 16 + r16];
        }
        float inv = 1.0f / ll;
        long orow = (gbase + q0 + row) * 192 + h * 32;
        aout[orow + r16]      = f2bf_fast(o0 * inv);
        aout[orow + 16 + r16] = f2bf_fast(o1 * inv);
      }
  }
}

// ---------------- local<->global fuse (in place on d_out) ------------------------
__global__ __launch_bounds__(192)
void fuse_kernel(float* __restrict__ dout, const float* __restrict__ l2gw,
                 const float* __restrict__ l2gb) {
  const int bw = blockIdx.x;
  const int b = bw >> 11, n = bw & 2047;
  const int c = threadIdx.x;
  const long gro = ((long)b * OUTR + L + n) * 192 + c;
  const float g = dout[gro];
  float acc = 0.f;
  for (int t = 0; t < 64; t++) {
    long xro = ((long)b * OUTR + win_l(n, t)) * 192 + c;
    float v = dout[xro] + g;
    dout[xro] = v;
    acc += v * l2gw[t];
  }
  dout[gro] = g + acc + l2gb[0];
}

extern "C" void kernel_launch(void* const* d_in, const int* in_sizes, int n_in,
                              void* d_out, int out_size, void* d_ws, size_t ws_size,
                              hipStream_t stream) {
  (void)in_sizes; (void)n_in; (void)out_size; (void)ws_size;
  const float* x      = (const float*)d_in[0];
  const float* gx     = (const float*)d_in[1];
  const float* qkv_w  = (const float*)d_in[2];
  const float* qkv_b  = (const float*)d_in[3];
  const float* proj_w = (const float*)d_in[4];
  const float* proj_b = (const float*)d_in[5];
  const float* rpb_l  = (const float*)d_in[6];
  const float* rpb_g  = (const float*)d_in[7];
  const float* n1g    = (const float*)d_in[8];
  const float* n1b    = (const float*)d_in[9];
  const float* n2g    = (const float*)d_in[10];
  const float* n2b    = (const float*)d_in[11];
  const float* fc1w   = (const float*)d_in[12];
  const float* fc1b   = (const float*)d_in[13];
  const float* fc2w   = (const float*)d_in[14];
  const float* fc2b   = (const float*)d_in[15];
  const float* l2gw   = (const float*)d_in[16];
  const float* l2gb   = (const float*)d_in[17];
  const int*   ridx_l = (const int*)d_in[18];
  const int*   ridx_g = (const int*)d_in[19];
  float* out = (float*)d_out;
  char* ws = (char*)d_ws;

  // ws layout:
  u16* wqkvT = (u16*)(ws + 0);             // 576*192*2 = 221184
  u16* wprojT= (u16*)(ws + 221184);        // 192*192*2 = 73728
  u16* wfc1T = (u16*)(ws + 294912);        // 768*192*2 = 294912
  u16* wfc2T = (u16*)(ws + 589824);        // 192*768*2 = 294912
  u16* biasL = (u16*)(ws + 884736);        // 6*64*64*2 = 49152
  u16* xn    = (u16*)(ws + 1048576);       // slotA: xn -> attL -> xn2
  u16* qkvL  = (u16*)(ws + 101711872ll);   // slotB: qkvL(302MB)
  u16* biasG = (u16*)(ws + 403701760ll);   // 50331648
  u16* attG  = (u16*)(ws + 454033408ll);   // 1572864
  u16* gn    = (u16*)(ws + 504365056ll);   // slotC: gn -> gn2
  u16* qkvG  = (u16*)(ws + 505937920ll);   // slotD
  u16* attL = xn;
  u16* xn2  = xn;
  u16* gn2  = gn;

  // 0. precompute tables (inputs only)
  wconv_kernel<<<dim3(3, 576),  dim3(64), 0, stream>>>(qkv_w,  wqkvT, 192, 576);
  wconv_kernel<<<dim3(3, 192),  dim3(64), 0, stream>>>(proj_w, wprojT, 192, 192);
  wconv_kernel<<<dim3(3, 768),  dim3(64), 0, stream>>>(fc1w,   wfc1T, 192, 768);
  wconv_kernel<<<dim3(12, 192), dim3(64), 0, stream>>>(fc2w,   wfc2T, 768, 192);
  lbias_kernel<<<dim3(96),      dim3(256), 0, stream>>>(ridx_l, rpb_l, biasL);
  gbias_kernel<<<dim3(12288),   dim3(256), 0, stream>>>(ridx_g, rpb_g, biasG);
  // 1. LN1 (both streams)
  ln_kernel<0><<<dim3(65536), dim3(256), 0, stream>>>(x,  n1g, n1b, xn);
  ln_kernel<0><<<dim3(1024),  dim3(256), 0, stream>>>(gx, n1g, n1b, gn);
  // 2. QKV projections (local: persistent-A M=64)
  gemmP_kernel<false,false,0,0,true><<<dim3(4096), dim3(256), 0, stream>>>(
      xn, wqkvT, qkv_b, nullptr, nullptr, qkvL, 576);
  gemm_kernel<false,false,0,0,true><<<dim3(9,32), dim3(256), 0, stream>>>(
      gn, wqkvT, qkv_b, nullptr, nullptr, qkvG, 4096, 576, 192);
  // 3. attention
  wattn_kernel<<<dim3(6144), dim3(256), 0, stream>>>(qkvL, biasL, attL);
  gattn_kernel<<<dim3(768),  dim3(256), 0, stream>>>(qkvG, biasG, attG);
  // 4. proj + residual -> d_out (x1, g1)
  gemmP_kernel<false,true,1,0,false><<<dim3(4096), dim3(256), 0, stream>>>(
      attL, wprojT, proj_b, x, out, nullptr, 192);
  gemm_kernel<false,true,2,0,false><<<dim3(3,32), dim3(256), 0, stream>>>(
      attG, wprojT, proj_b, gx, out, nullptr, 4096, 192, 192);
  // 5. local<->global fuse, in place on d_out (x2, g2)
  fuse_kernel<<<dim3(4096), dim3(192), 0, stream>>>(out, l2gw, l2gb);
  // 6. LN2 (both streams, read from d_out)
  ln_kernel<1><<<dim3(65536), dim3(256), 0, stream>>>((const float*)out, n2g, n2b, xn2);
  ln_kernel<2><<<dim3(1024),  dim3(256), 0, stream>>>((const float*)out, n2g, n2b, gn2);
  // 7+8. fused MLP v8 (chunk-phase stagger), both streams
  fusedmlp_kernel<1><<<dim3(4096), dim3(512), 0, stream>>>(
      xn2, wfc1T, fc1b, wfc2T, fc2b, out);
  fusedmlp_kernel<2><<<dim3(64), dim3(512), 0, stream>>>(
      gn2, wfc1T, fc1b, wfc2T, fc2b, out);
}